// Round 9
// baseline (316.672 us; speedup 1.0000x reference)
//
#include <hip/hip_runtime.h>
#include <math.h>

#define TDIM   1032
#define DIM    1024
#define SLEN   2048
#define BATCH  2
#define NROWS  (SLEN*BATCH)   // 4096
#define NHEAD  16
#define HD     64

typedef unsigned short u16;
typedef short short8 __attribute__((ext_vector_type(8)));
typedef short bf16x4 __attribute__((ext_vector_type(4)));
typedef float f32x4  __attribute__((ext_vector_type(4)));
typedef unsigned uint2v __attribute__((ext_vector_type(2)));

#define CSCALE 0.18033688011112042f   // 0.125 * log2(e), folded into Q

__device__ inline unsigned fbits(float x) {
    union { float f; unsigned u; } v; v.f = x; return v.u;
}
__device__ inline float asfloat(unsigned u) {
    union { unsigned u; float f; } v; v.u = u; return v.f;
}
__device__ inline u16 f2bf_rne(float x) {
    unsigned u = fbits(x);
    unsigned r = u + 0x7fffu + ((u >> 16) & 1u);
    return (u16)(r >> 16);
}
__device__ inline float bf2f(u16 b) { return asfloat(((unsigned)b) << 16); }
__device__ inline void dma16(const u16* g, u16* l) {
    __builtin_amdgcn_global_load_lds(
        (const __attribute__((address_space(1))) void*)g,
        (__attribute__((address_space(3))) void*)l, 16, 0, 0);
}

// ---------------------------------------------------------------------------
// Shared bodies for the fused prep kernel and the standalone fallback.
// ---------------------------------------------------------------------------
__device__ inline void conv_body(
    int t, int bx, int by, int tid,
    const float* __restrict__ tmpl, const float* __restrict__ cw,
    const float* __restrict__ cb,
    u16* __restrict__ Wh, u16* __restrict__ Wl, float* scw)
{
    if (tid < 81) scw[tid] = cw[tid];
    __syncthreads();
    int i = bx * 256 + tid;
    int o4 = by * 4;
    float cbv = cb[0];
    float acc[4] = {cbv, cbv, cbv, cbv};
    #pragma unroll
    for (int ry = 0; ry < 12; ++ry) {
        const float* trow = tmpl + (size_t)(o4 + ry) * TDIM + i;
        float tv[9];
        #pragma unroll
        for (int dx = 0; dx < 9; ++dx) tv[dx] = trow[dx];
        #pragma unroll
        for (int oo = 0; oo < 4; ++oo) {
            int dy = ry - oo;
            if (dy >= 0 && dy <= 8) {
                #pragma unroll
                for (int dx = 0; dx < 9; ++dx)
                    acc[oo] = fmaf(scw[dy * 9 + dx], tv[dx], acc[oo]);
            }
        }
    }
    #pragma unroll
    for (int oo = 0; oo < 4; ++oo) {
        size_t idx = (size_t)t * DIM * DIM + (size_t)(o4 + oo) * DIM + i;
        u16 h = f2bf_rne(acc[oo]);
        Wh[idx] = h;
        Wl[idx] = f2bf_rne(acc[oo] - bf2f(h));
    }
}

__device__ inline void xsplit_body(
    int t, int bx, int tid,
    const float* __restrict__ X, u16* __restrict__ Xh, u16* __restrict__ Xl)
{
    u16* oh = Xh + (size_t)t * NROWS * DIM;
    u16* ol = Xl + (size_t)t * NROWS * DIM;
    size_t base = ((size_t)bx * 256 + tid) * 8;
    float4 a = *(const float4*)(X + base);
    float4 b = *(const float4*)(X + base + 4);
    float v[8] = {a.x, a.y, a.z, a.w, b.x, b.y, b.z, b.w};
    short8 hv, lv;
    #pragma unroll
    for (int e = 0; e < 8; ++e) {
        unsigned u = fbits(v[e]);
        hv[e] = (short)(u >> 16);
        float l = v[e] - asfloat(u & 0xffff0000u);
        lv[e] = (short)(fbits(l) >> 16);
    }
    *(short8*)(oh + base) = hv;
    *(short8*)(ol + base) = lv;
}

// ---------------------------------------------------------------------------
// Kernel 1 (fused): conv (blocks 0..3071) + xsplit (blocks 3072..9215).
// Independent work streams co-scheduled instead of serialized.
// ---------------------------------------------------------------------------
__global__ __launch_bounds__(256) void prep_kernel(
    const float* __restrict__ tmpl,
    const float* __restrict__ cw0, const float* __restrict__ cb0,
    const float* __restrict__ cw1, const float* __restrict__ cb1,
    const float* __restrict__ cw2, const float* __restrict__ cb2,
    u16* __restrict__ Wh, u16* __restrict__ Wl,
    const float* __restrict__ x0, const float* __restrict__ x1,
    const float* __restrict__ x2,
    u16* __restrict__ Xh, u16* __restrict__ Xl)
{
    __shared__ float scw[81];
    int bid = blockIdx.x;
    int tid = threadIdx.x;
    if (bid < 3072) {
        int t = bid >> 10;
        int rem = bid & 1023;
        const float* cw = (t == 0) ? cw0 : ((t == 1) ? cw1 : cw2);
        const float* cb = (t == 0) ? cb0 : ((t == 1) ? cb1 : cb2);
        conv_body(t, rem & 3, rem >> 2, tid, tmpl, cw, cb, Wh, Wl, scw);
    } else {
        int idx = bid - 3072;
        int t = idx >> 11;
        const float* X = (t == 0) ? x0 : ((t == 1) ? x1 : x2);
        xsplit_body(t, idx & 2047, tid, X, Xh, Xl);
    }
}

// ---------------------------------------------------------------------------
// Kernel 1-fallback: conv only (used when ws can't hold Xh/Xl).
// ---------------------------------------------------------------------------
__global__ __launch_bounds__(256) void conv_weight_kernel(
    const float* __restrict__ tmpl,
    const float* __restrict__ cw0, const float* __restrict__ cb0,
    const float* __restrict__ cw1, const float* __restrict__ cb1,
    const float* __restrict__ cw2, const float* __restrict__ cb2,
    u16* __restrict__ Wh, u16* __restrict__ Wl)
{
    __shared__ float scw[81];
    int t = blockIdx.z;
    const float* cw = (t == 0) ? cw0 : ((t == 1) ? cw1 : cw2);
    const float* cb = (t == 0) ? cb0 : ((t == 1) ? cb1 : cb2);
    conv_body(t, blockIdx.x, blockIdx.y, threadIdx.x, tmpl, cw, cb, Wh, Wl, scw);
}

// ---------------------------------------------------------------------------
// Kernel 2 (presplit path): pure-staging MFMA GEMM, m97 shape.
// ---------------------------------------------------------------------------
__global__ __launch_bounds__(256, 3) void qkv_mfma_gemm_ps(
    const u16* __restrict__ Xhg, const u16* __restrict__ Xlg,
    const u16* __restrict__ Whg, const u16* __restrict__ Wlg,
    const float* __restrict__ b0, const float* __restrict__ b1,
    const float* __restrict__ b2,
    u16* __restrict__ Qh, u16* __restrict__ Ql,
    u16* __restrict__ Kh, u16* __restrict__ Kl,
    u16* __restrict__ Vb)
{
    unsigned flat = blockIdx.x + 8u * blockIdx.y + 256u * blockIdx.z; // 0..767
    unsigned swz = (flat & 7u) * 96u + (flat >> 3);
    int t = swz >> 8;
    int n0 = (swz & 7u) * 128;
    int m0 = ((swz >> 3) & 31u) * 128;

    const u16* Ah_g = Xhg + (size_t)t * NROWS * DIM;
    const u16* Al_g = Xlg + (size_t)t * NROWS * DIM;
    const u16* Bh_g = Whg + (size_t)t * DIM * DIM;
    const u16* Bl_g = Wlg + (size_t)t * DIM * DIM;
    const float* bias = (t == 0) ? b0 : ((t == 1) ? b1 : b2);

    __shared__ __align__(16) u16 lds[16384];
    u16* sAh = lds;
    u16* sAl = lds + 4096;
    u16* sBh = lds + 8192;
    u16* sBl = lds + 12288;

    int tid = threadIdx.x;
    int w = tid >> 6, lane = tid & 63;
    int c = lane & 15, quad = lane >> 4;
    int mh = (w >> 1) * 64, nh = (w & 1) * 64;

    int srow = lane >> 2, sgr = lane & 3;
    int ssw = sgr ^ ((srow >> 1) & 3);        // pre-swizzled source chunk

    f32x4 acc[4][4];
    #pragma unroll
    for (int i = 0; i < 4; ++i)
        #pragma unroll
        for (int j = 0; j < 4; ++j)
            #pragma unroll
            for (int r = 0; r < 4; ++r) acc[i][j][r] = 0.0f;

    float bias_v[4];
    #pragma unroll
    for (int tn = 0; tn < 4; ++tn) bias_v[tn] = bias[n0 + nh + tn * 16 + c];

    #define STAGE(kg) do {                                                     \
        _Pragma("unroll")                                                      \
        for (int i_ = 0; i_ < 2; ++i_) {                                       \
            int rb = w * 32 + i_ * 16;                                         \
            size_t ro = (size_t)(n0 + rb + srow) * DIM + ((kg) + ssw) * 8;     \
            dma16(Bh_g + ro, sBh + rb * 32);                                   \
            dma16(Bl_g + ro, sBl + rb * 32);                                   \
            size_t ao = (size_t)(m0 + rb + srow) * DIM + ((kg) + ssw) * 8;     \
            dma16(Ah_g + ao, sAh + rb * 32);                                   \
            dma16(Al_g + ao, sAl + rb * 32);                                   \
        }                                                                      \
    } while (0)

    STAGE(0);

    for (int it = 0; it < 32; ++it) {
        __syncthreads();                      // staged tiles landed

        short8 ah[4], al[4], bh[4], bl[4];
        int rsw = (quad ^ ((c >> 1) & 3)) * 8;
        #pragma unroll
        for (int tt = 0; tt < 4; ++tt) {
            int mi = (mh + tt * 16 + c) * 32 + rsw;
            ah[tt] = *(short8*)(sAh + mi);
            al[tt] = *(short8*)(sAl + mi);
            int ni = (nh + tt * 16 + c) * 32 + rsw;
            bh[tt] = *(short8*)(sBh + ni);
            bl[tt] = *(short8*)(sBl + ni);
        }
        __syncthreads();                      // LDS free for next stage

        if (it < 31) STAGE((it + 1) * 4);

        #pragma unroll
        for (int tm = 0; tm < 4; ++tm)
            #pragma unroll
            for (int tn = 0; tn < 4; ++tn) {
                acc[tm][tn] = __builtin_amdgcn_mfma_f32_16x16x32_bf16(
                    ah[tm], bh[tn], acc[tm][tn], 0, 0, 0);
                acc[tm][tn] = __builtin_amdgcn_mfma_f32_16x16x32_bf16(
                    ah[tm], bl[tn], acc[tm][tn], 0, 0, 0);
                acc[tm][tn] = __builtin_amdgcn_mfma_f32_16x16x32_bf16(
                    al[tm], bh[tn], acc[tm][tn], 0, 0, 0);
            }
    }
    #undef STAGE

    // ---- epilogue: trunc-hi/lo split; Q pre-scaled by CSCALE ----
    if (t < 2) {
        u16* Yh = (t == 0) ? Qh : Kh;
        u16* Yl = (t == 0) ? Ql : Kl;
        float qs = (t == 0) ? CSCALE : 1.0f;
        #pragma unroll
        for (int tm = 0; tm < 4; ++tm)
            #pragma unroll
            for (int r = 0; r < 4; ++r) {
                int m = m0 + mh + tm * 16 + quad * 4 + r;
                #pragma unroll
                for (int tn = 0; tn < 4; ++tn) {
                    int n = n0 + nh + tn * 16 + c;
                    float o = (acc[tm][tn][r] + bias_v[tn]) * qs;
                    unsigned bo = fbits(o);
                    Yh[(size_t)m * DIM + n] = (u16)(bo >> 16);
                    float l = o - asfloat(bo & 0xffff0000u);
                    Yl[(size_t)m * DIM + n] = (u16)(fbits(l) >> 16);
                }
            }
    } else {
        #pragma unroll
        for (int tm = 0; tm < 4; ++tm)
            #pragma unroll
            for (int r = 0; r < 4; ++r) {
                int m = m0 + mh + tm * 16 + quad * 4 + r;
                #pragma unroll
                for (int tn = 0; tn < 4; ++tn) {
                    int n = n0 + nh + tn * 16 + c;
                    Vb[(size_t)m * DIM + n] =
                        (u16)(fbits(acc[tm][tn][r] + bias_v[tn]) >> 16);
                }
            }
    }
}

// ---------------------------------------------------------------------------
// Kernel 2 (fallback): in-loop A split. Used only when ws can't hold Xh/Xl.
// ---------------------------------------------------------------------------
__global__ __launch_bounds__(256, 3) void qkv_mfma_gemm_fb(
    const float* __restrict__ x0, const float* __restrict__ x1,
    const float* __restrict__ x2,
    const u16* __restrict__ Whg, const u16* __restrict__ Wlg,
    const float* __restrict__ b0, const float* __restrict__ b1,
    const float* __restrict__ b2,
    u16* __restrict__ Qh, u16* __restrict__ Ql,
    u16* __restrict__ Kh, u16* __restrict__ Kl,
    u16* __restrict__ Vb)
{
    unsigned flat = blockIdx.x + 8u * blockIdx.y + 256u * blockIdx.z;
    unsigned swz = (flat & 7u) * 96u + (flat >> 3);
    int t = swz >> 8;
    int n0 = (swz & 7u) * 128;
    int m0 = ((swz >> 3) & 31u) * 128;

    const float* X    = (t == 0) ? x0 : ((t == 1) ? x1 : x2);
    const u16* Bh_g   = Whg + (size_t)t * DIM * DIM;
    const u16* Bl_g   = Wlg + (size_t)t * DIM * DIM;
    const float* bias = (t == 0) ? b0 : ((t == 1) ? b1 : b2);

    __shared__ __align__(16) u16 lds[16384];
    u16* sAh = lds;
    u16* sAl = lds + 4096;
    u16* sBh = lds + 8192;
    u16* sBl = lds + 12288;

    int tid = threadIdx.x;
    int w = tid >> 6, lane = tid & 63;
    int c = lane & 15, quad = lane >> 4;
    int mh = (w >> 1) * 64, nh = (w & 1) * 64;

    int arow = w * 32 + (lane & 31);
    int acol = (lane >> 5) * 16;
    const float* aptr = X + (size_t)(m0 + arow) * DIM + acol;
    int awz = (arow >> 1) & 3;

    int srow = lane >> 2, sgr = lane & 3;
    int bsw = sgr ^ ((srow >> 1) & 3);

    f32x4 acc[4][4];
    #pragma unroll
    for (int i = 0; i < 4; ++i)
        #pragma unroll
        for (int j = 0; j < 4; ++j)
            #pragma unroll
            for (int r = 0; r < 4; ++r) acc[i][j][r] = 0.0f;

    float bias_v[4];
    #pragma unroll
    for (int tn = 0; tn < 4; ++tn) bias_v[tn] = bias[n0 + nh + tn * 16 + c];

    float4 xa[4];
    #pragma unroll
    for (int i = 0; i < 2; ++i) {
        int rb = w * 32 + i * 16;
        const u16* gh = Bh_g + (size_t)(n0 + rb + srow) * DIM + bsw * 8;
        const u16* gl = Bl_g + (size_t)(n0 + rb + srow) * DIM + bsw * 8;
        dma16(gh, sBh + rb * 32);
        dma16(gl, sBl + rb * 32);
    }
    #pragma unroll
    for (int j = 0; j < 4; ++j) xa[j] = *(const float4*)(aptr + j * 4);

    for (int it = 0; it < 32; ++it) {
        #pragma unroll
        for (int g = 0; g < 2; ++g) {
            float v[8] = { xa[2*g].x, xa[2*g].y, xa[2*g].z, xa[2*g].w,
                           xa[2*g+1].x, xa[2*g+1].y, xa[2*g+1].z, xa[2*g+1].w };
            short8 hv, lv;
            #pragma unroll
            for (int e = 0; e < 8; ++e) {
                unsigned u = fbits(v[e]);
                hv[e] = (short)(u >> 16);
                float l = v[e] - asfloat(u & 0xffff0000u);
                lv[e] = (short)(fbits(l) >> 16);
            }
            int chunk = (((lane >> 5) * 2 + g) ^ awz) * 8;
            *(short8*)(sAh + arow * 32 + chunk) = hv;
            *(short8*)(sAl + arow * 32 + chunk) = lv;
        }
        __syncthreads();

        short8 ah[4], al[4], bh[4], bl[4];
        int rsw = (quad ^ ((c >> 1) & 3)) * 8;
        #pragma unroll
        for (int tt = 0; tt < 4; ++tt) {
            int mi = (mh + tt * 16 + c) * 32 + rsw;
            ah[tt] = *(short8*)(sAh + mi);
            al[tt] = *(short8*)(sAl + mi);
            int ni = (nh + tt * 16 + c) * 32 + rsw;
            bh[tt] = *(short8*)(sBh + ni);
            bl[tt] = *(short8*)(sBl + ni);
        }
        __syncthreads();

        if (it < 31) {
            int kg = (it + 1) * 4;
            #pragma unroll
            for (int i = 0; i < 2; ++i) {
                int rb = w * 32 + i * 16;
                const u16* gh = Bh_g + (size_t)(n0 + rb + srow) * DIM + (kg + bsw) * 8;
                const u16* gl = Bl_g + (size_t)(n0 + rb + srow) * DIM + (kg + bsw) * 8;
                dma16(gh, sBh + rb * 32);
                dma16(gl, sBl + rb * 32);
            }
            #pragma unroll
            for (int j = 0; j < 4; ++j)
                xa[j] = *(const float4*)(aptr + (it + 1) * 32 + j * 4);
        }

        #pragma unroll
        for (int tm = 0; tm < 4; ++tm)
            #pragma unroll
            for (int tn = 0; tn < 4; ++tn) {
                acc[tm][tn] = __builtin_amdgcn_mfma_f32_16x16x32_bf16(
                    ah[tm], bh[tn], acc[tm][tn], 0, 0, 0);
                acc[tm][tn] = __builtin_amdgcn_mfma_f32_16x16x32_bf16(
                    ah[tm], bl[tn], acc[tm][tn], 0, 0, 0);
                acc[tm][tn] = __builtin_amdgcn_mfma_f32_16x16x32_bf16(
                    al[tm], bh[tn], acc[tm][tn], 0, 0, 0);
            }
    }

    if (t < 2) {
        u16* Yh = (t == 0) ? Qh : Kh;
        u16* Yl = (t == 0) ? Ql : Kl;
        float qs = (t == 0) ? CSCALE : 1.0f;
        #pragma unroll
        for (int tm = 0; tm < 4; ++tm)
            #pragma unroll
            for (int r = 0; r < 4; ++r) {
                int m = m0 + mh + tm * 16 + quad * 4 + r;
                #pragma unroll
                for (int tn = 0; tn < 4; ++tn) {
                    int n = n0 + nh + tn * 16 + c;
                    float o = (acc[tm][tn][r] + bias_v[tn]) * qs;
                    unsigned bo = fbits(o);
                    Yh[(size_t)m * DIM + n] = (u16)(bo >> 16);
                    float l = o - asfloat(bo & 0xffff0000u);
                    Yl[(size_t)m * DIM + n] = (u16)(fbits(l) >> 16);
                }
            }
    } else {
        #pragma unroll
        for (int tm = 0; tm < 4; ++tm)
            #pragma unroll
            for (int r = 0; r < 4; ++r) {
                int m = m0 + mh + tm * 16 + quad * 4 + r;
                #pragma unroll
                for (int tn = 0; tn < 4; ++tn) {
                    int n = n0 + nh + tn * 16 + c;
                    Vb[(size_t)m * DIM + n] =
                        (u16)(fbits(acc[tm][tn][r] + bias_v[tn]) >> 16);
                }
            }
    }
}

// ---------------------------------------------------------------------------
// Kernel 3: V bf16 [s*B+b][h*64+d] -> Vt bf16 [b][h][d][s]
// ---------------------------------------------------------------------------
__global__ __launch_bounds__(256) void vt_kernel(
    const u16* __restrict__ Vb, u16* __restrict__ Vt)
{
    int b = blockIdx.z, h = blockIdx.y, s0 = blockIdx.x * 64;
    __shared__ __align__(16) u16 tile[64][80];
    int tid = threadIdx.x;
    int sl = tid >> 2, d0 = (tid & 3) * 16;
    const u16* src = Vb + (size_t)((s0 + sl) * BATCH + b) * DIM + h * HD + d0;
    short8 v0 = *(const short8*)src;
    short8 v1 = *(const short8*)(src + 8);
    #pragma unroll
    for (int j = 0; j < 8; ++j) {
        tile[d0 + j][sl] = (u16)v0[j];
        tile[d0 + 8 + j][sl] = (u16)v1[j];
    }
    __syncthreads();
    int d = tid >> 2, sc0 = (tid & 3) * 16;
    u16* dst = Vt + (size_t)((b * NHEAD + h) * HD + d) * SLEN + s0 + sc0;
    *(short8*)dst = *(const short8*)&tile[d][sc0];
    *(short8*)(dst + 8) = *(const short8*)&tile[d][sc0 + 8];
}

// ---------------------------------------------------------------------------
// Kernel 4: MFMA flash attention v10 — v9 + deferred l-reduction: the
// per-iteration 2x shfl_xor for the l-sum (LDS-pipe ops; pipe measured ~83%
// busy) are replaced by a per-lane partial (lanes sharing q=c have identical
// m/alpha history) reduced once in the epilogue.
// ---------------------------------------------------------------------------
__global__ __launch_bounds__(512, 4) void attn_mfma_kernel(
    const u16* __restrict__ Qh, const u16* __restrict__ Ql,
    const u16* __restrict__ Kh, const u16* __restrict__ Kl,
    const u16* __restrict__ Vt, float* __restrict__ out)
{
    unsigned flat = blockIdx.x + 16u * blockIdx.y + 256u * blockIdx.z; // 0..511
    unsigned swz = (flat & 7u) * 64u + (flat >> 3);
    int q0 = (swz & 15u) * 128;
    int h = (swz >> 4) & 15u;
    int b = swz >> 8;

    int tid = threadIdx.x;
    int w = tid >> 6, lane = tid & 63;
    int c = lane & 15, quad = lane >> 4;

    __shared__ __align__(16) u16 sbuf[2][3][4096];
    // wave-private P: 16 q-rows x 64 keys, chunk8-swizzled = 2 KB/wave
    __shared__ __align__(16) u16 sP[8][1024];

    short8 qhf[2], qlf[2];
    {
        int s = q0 + w * 16 + c;
        size_t base = (size_t)(s * BATCH + b) * DIM + h * HD + quad * 8;
        qhf[0] = *(const short8*)(Qh + base);
        qhf[1] = *(const short8*)(Qh + base + 32);
        qlf[0] = *(const short8*)(Ql + base);
        qlf[1] = *(const short8*)(Ql + base + 32);
    }

    f32x4 acc[4];
    #pragma unroll
    for (int i = 0; i < 4; ++i)
        #pragma unroll
        for (int r = 0; r < 4; ++r) acc[i][r] = 0.0f;
    float m_run = -1e38f, lsum = 0.0f;   // lsum: per-lane partial (own 16 keys)

    int r3 = lane >> 3, c3 = lane & 7;
    int sw = c3 ^ r3;
    const size_t bhofs = (size_t)(b * NHEAD + h) * HD;

    #define ISSUE_DMA(n0v, bufv) do {                                          \
        int row_ = w * 8 + r3;                                                 \
        size_t gk = (size_t)(((n0v) + row_) * BATCH + b) * DIM + h * HD + sw * 8; \
        dma16(Kh + gk, &sbuf[bufv][0][w * 512]);                               \
        dma16(Kl + gk, &sbuf[bufv][1][w * 512]);                               \
        size_t gv = (bhofs + row_) * SLEN + (n0v) + sw * 8;                    \
        dma16(Vt + gv, &sbuf[bufv][2][w * 512]);                               \
    } while (0)

    ISSUE_DMA(0, 0);

    for (int it = 0; it < 32; ++it) {
        int cur = it & 1;
        __syncthreads();
        if (it < 31) ISSUE_DMA((it + 1) * 64, cur ^ 1);

        const u16* bKh = sbuf[cur][0];
        const u16* bKl = sbuf[cur][1];
        const u16* bVt = sbuf[cur][2];

        // ---- T = K·Q^T : lane gets T[key=ct*16+quad*4+r][q=c] ----
        f32x4 sc[4];
        #pragma unroll
        for (int ct = 0; ct < 4; ++ct) {
            int row = ct * 16 + c, rw = row & 7;
            int kb = row * 64;
            short8 kh0 = *(const short8*)(bKh + kb + ((quad ^ rw) * 8));
            short8 kh1 = *(const short8*)(bKh + kb + (((4 + quad) ^ rw) * 8));
            short8 kl0 = *(const short8*)(bKl + kb + ((quad ^ rw) * 8));
            short8 kl1 = *(const short8*)(bKl + kb + (((4 + quad) ^ rw) * 8));
            __builtin_amdgcn_s_setprio(1);
            f32x4 s = {0.0f, 0.0f, 0.0f, 0.0f};
            s = __builtin_amdgcn_mfma_f32_16x16x32_bf16(kh0, qhf[0], s, 0, 0, 0);
            s = __builtin_amdgcn_mfma_f32_16x16x32_bf16(kh1, qhf[1], s, 0, 0, 0);
            s = __builtin_amdgcn_mfma_f32_16x16x32_bf16(kh0, qlf[0], s, 0, 0, 0);
            s = __builtin_amdgcn_mfma_f32_16x16x32_bf16(kh1, qlf[1], s, 0, 0, 0);
            s = __builtin_amdgcn_mfma_f32_16x16x32_bf16(kl0, qhf[0], s, 0, 0, 0);
            s = __builtin_amdgcn_mfma_f32_16x16x32_bf16(kl1, qhf[1], s, 0, 0, 0);
            __builtin_amdgcn_s_setprio(0);
            sc[ct] = s;
        }

        // ---- V fragments hoisted: ds_read latency hides under softmax ----
        short8 vv[4][2];
        #pragma unroll
        for (int ctd = 0; ctd < 4; ++ctd) {
            int vrow = ctd * 16 + c, vrw = vrow & 7;
            int vb = vrow * 64;
            vv[ctd][0] = *(const short8*)(bVt + vb + ((quad ^ vrw) * 8));
            vv[ctd][1] = *(const short8*)(bVt + vb + (((4 + quad) ^ vrw) * 8));
        }

        // ---- online softmax + P pack -> wave-private swizzled LDS ----
        u16* wp = sP[w];
        short8 pf0, pf1;
        {
            float m00 = fmaxf(fmaxf(sc[0][0], sc[0][1]), fmaxf(sc[0][2], sc[0][3]));
            float m01 = fmaxf(fmaxf(sc[1][0], sc[1][1]), fmaxf(sc[1][2], sc[1][3]));
            float m10 = fmaxf(fmaxf(sc[2][0], sc[2][1]), fmaxf(sc[2][2], sc[2][3]));
            float m11 = fmaxf(fmaxf(sc[3][0], sc[3][1]), fmaxf(sc[3][2], sc[3][3]));
            float pm = fmaxf(fmaxf(m00, m01), fmaxf(m10, m11));
            pm = fmaxf(pm, __shfl_xor(pm, 16));
            pm = fmaxf(pm, __shfl_xor(pm, 32));
            float mnew = fmaxf(m_run, pm);
            bool noresc = __all(pm <= m_run);
            if (!noresc) {
                float al = __builtin_amdgcn_exp2f(m_run - mnew);
                #pragma unroll
                for (int ctd = 0; ctd < 4; ++ctd)
                    #pragma unroll
                    for (int r = 0; r < 4; ++r) acc[ctd][r] *= al;
                lsum *= al;
            }
            m_run = mnew;

            float psp[4];
            int prow = c * 64;
            #pragma unroll
            for (int ct = 0; ct < 4; ++ct) {
                float p0 = __builtin_amdgcn_exp2f(sc[ct][0] - mnew);
                float p1 = __builtin_amdgcn_exp2f(sc[ct][1] - mnew);
                float p2 = __builtin_amdgcn_exp2f(sc[ct][2] - mnew);
                float p3 = __builtin_amdgcn_exp2f(sc[ct][3] - mnew);
                psp[ct] = (p0 + p1) + (p2 + p3);
                uint2v pk;
                pk.x = __builtin_amdgcn_perm(fbits(p1), fbits(p0), 0x07060302u);
                pk.y = __builtin_amdgcn_perm(fbits(p3), fbits(p2), 0x07060302u);
                int phys = (ct * 2 + (quad >> 1)) ^ (c & 7);
                *(uint2v*)(wp + prow + phys * 8 + (quad & 1) * 4) = pk;
            }
            lsum += (psp[0] + psp[1]) + (psp[2] + psp[3]);

            int rw = c & 7;
            pf0 = *(const short8*)(wp + prow + ((quad ^ rw) * 8));
            pf1 = *(const short8*)(wp + prow + (((4 + quad) ^ rw) * 8));
        }

        // ---- O^T += V^T·P^T : A=vv (V^T rows d), B=pf (P^T cols q=c) ----
        __builtin_amdgcn_s_setprio(1);
        #pragma unroll
        for (int ctd = 0; ctd < 4; ++ctd) {
            acc[ctd] = __builtin_amdgcn_mfma_f32_16x16x32_bf16(
                vv[ctd][0], pf0, acc[ctd], 0, 0, 0);
            acc[ctd] = __builtin_amdgcn_mfma_f32_16x16x32_bf16(
                vv[ctd][1], pf1, acc[ctd], 0, 0, 0);
        }
        __builtin_amdgcn_s_setprio(0);
    }
    #undef ISSUE_DMA

    // ---- epilogue: reduce l across the 4 quads (q=c), float4 stores ----
    {
        float lt = lsum;
        lt += __shfl_xor(lt, 16);
        lt += __shfl_xor(lt, 32);
        float rli = 1.0f / lt;
        int s = q0 + w * 16 + c;
        float* obase = out + (size_t)(s * BATCH + b) * DIM + h * HD + quad * 4;
        #pragma unroll
        for (int ctd = 0; ctd < 4; ++ctd) {
            float4 ov;
            ov.x = acc[ctd][0] * rli;
            ov.y = acc[ctd][1] * rli;
            ov.z = acc[ctd][2] * rli;
            ov.w = acc[ctd][3] * rli;
            *(float4*)(obase + ctd * 16) = ov;
        }
    }
}

// ---------------------------------------------------------------------------
extern "C" void kernel_launch(void* const* d_in, const int* in_sizes, int n_in,
                              void* d_out, int out_size, void* d_ws, size_t ws_size,
                              hipStream_t stream)
{
    const float* query = (const float*)d_in[0];
    const float* key_  = (const float*)d_in[1];
    const float* value = (const float*)d_in[2];
    const float* tmpl  = (const float*)d_in[3];
    const float* wq_cw = (const float*)d_in[4];
    const float* wq_cb = (const float*)d_in[5];
    const float* wq_b  = (const float*)d_in[6];
    const float* wk_cw = (const float*)d_in[7];
    const float* wk_cb = (const float*)d_in[8];
    const float* wk_b  = (const float*)d_in[9];
    const float* wv_cw = (const float*)d_in[10];
    const float* wv_cb = (const float*)d_in[11];
    const float* wv_b  = (const float*)d_in[12];

    char* ws = (char*)d_ws;
    u16* Wh = (u16*)(ws);
    u16* Wl = (u16*)(ws + 6291456);
    u16* Qh = (u16*)(ws + 12582912);
    u16* Ql = (u16*)(ws + 20971520);
    u16* Kh = (u16*)(ws + 29360128);
    u16* Kl = (u16*)(ws + 37748736);
    u16* Vb = (u16*)(ws + 46137344);
    u16* Vt = (u16*)(ws + 54525952);
    u16* Xh = (u16*)(ws + 62914560);           // 3*4096*1024*2 = 25165824
    u16* Xl = (u16*)(ws + 88080384);           // ends at 113246208
    float* out = (float*)d_out;

    bool presplit = ws_size >= 113246208ull;

    if (presplit) {
        prep_kernel<<<dim3(9216), 256, 0, stream>>>(
            tmpl, wq_cw, wq_cb, wk_cw, wk_cb, wv_cw, wv_cb, Wh, Wl,
            query, key_, value, Xh, Xl);
        qkv_mfma_gemm_ps<<<dim3(DIM / 128, NROWS / 128, 3), 256, 0, stream>>>(
            Xh, Xl, Wh, Wl, wq_b, wk_b, wv_b, Qh, Ql, Kh, Kl, Vb);
    } else {
        conv_weight_kernel<<<dim3(DIM / 256, DIM / 4, 3), 256, 0, stream>>>(
            tmpl, wq_cw, wq_cb, wk_cw, wk_cb, wv_cw, wv_cb, Wh, Wl);
        qkv_mfma_gemm_fb<<<dim3(DIM / 128, NROWS / 128, 3), 256, 0, stream>>>(
            query, key_, value, Wh, Wl, wq_b, wk_b, wv_b, Qh, Ql, Kh, Kl, Vb);
    }

    vt_kernel<<<dim3(SLEN / 64, NHEAD, BATCH), 256, 0, stream>>>(Vb, Vt);

    attn_mfma_kernel<<<dim3(SLEN / 128, NHEAD, BATCH), 512, 0, stream>>>(
        Qh, Ql, Kh, Kl, Vt, out);
}

// Round 10
// 292.380 us; speedup vs baseline: 1.0831x; 1.0831x over previous
//
#include <hip/hip_runtime.h>
#include <math.h>

#define TDIM   1032
#define DIM    1024
#define SLEN   2048
#define BATCH  2
#define NROWS  (SLEN*BATCH)   // 4096
#define NHEAD  16
#define HD     64

typedef unsigned short u16;
typedef short short8 __attribute__((ext_vector_type(8)));
typedef short bf16x4 __attribute__((ext_vector_type(4)));
typedef float f32x4  __attribute__((ext_vector_type(4)));
typedef unsigned uint2v __attribute__((ext_vector_type(2)));

#define CSCALE 0.18033688011112042f   // 0.125 * log2(e), folded into Q

__device__ inline unsigned fbits(float x) {
    union { float f; unsigned u; } v; v.f = x; return v.u;
}
__device__ inline float asfloat(unsigned u) {
    union { unsigned u; float f; } v; v.u = u; return v.f;
}
__device__ inline u16 f2bf_rne(float x) {
    unsigned u = fbits(x);
    unsigned r = u + 0x7fffu + ((u >> 16) & 1u);
    return (u16)(r >> 16);
}
__device__ inline float bf2f(u16 b) { return asfloat(((unsigned)b) << 16); }
__device__ inline void dma16(const u16* g, u16* l) {
    __builtin_amdgcn_global_load_lds(
        (const __attribute__((address_space(1))) void*)g,
        (__attribute__((address_space(3))) void*)l, 16, 0, 0);
}

// ---------------------------------------------------------------------------
// Kernel 1: conv 9x9 over template -> Wh/Wl bf16 hi/lo split directly.
// (Separate from xsplit — R9 proved fusing them costs ~24 µs e2e.)
// ---------------------------------------------------------------------------
__global__ __launch_bounds__(256) void conv_weight_kernel(
    const float* __restrict__ tmpl,
    const float* __restrict__ cw0, const float* __restrict__ cb0,
    const float* __restrict__ cw1, const float* __restrict__ cb1,
    const float* __restrict__ cw2, const float* __restrict__ cb2,
    u16* __restrict__ Wh, u16* __restrict__ Wl)
{
    int t = blockIdx.z;
    const float* cw = (t == 0) ? cw0 : ((t == 1) ? cw1 : cw2);
    const float* cb = (t == 0) ? cb0 : ((t == 1) ? cb1 : cb2);
    __shared__ float scw[81];
    if (threadIdx.x < 81) scw[threadIdx.x] = cw[threadIdx.x];
    __syncthreads();
    int i = blockIdx.x * 256 + threadIdx.x;
    int o4 = blockIdx.y * 4;
    float cbv = cb[0];
    float acc[4] = {cbv, cbv, cbv, cbv};
    #pragma unroll
    for (int ry = 0; ry < 12; ++ry) {
        const float* trow = tmpl + (size_t)(o4 + ry) * TDIM + i;
        float tv[9];
        #pragma unroll
        for (int dx = 0; dx < 9; ++dx) tv[dx] = trow[dx];
        #pragma unroll
        for (int oo = 0; oo < 4; ++oo) {
            int dy = ry - oo;
            if (dy >= 0 && dy <= 8) {
                #pragma unroll
                for (int dx = 0; dx < 9; ++dx)
                    acc[oo] = fmaf(scw[dy * 9 + dx], tv[dx], acc[oo]);
            }
        }
    }
    #pragma unroll
    for (int oo = 0; oo < 4; ++oo) {
        size_t idx = (size_t)t * DIM * DIM + (size_t)(o4 + oo) * DIM + i;
        u16 h = f2bf_rne(acc[oo]);
        Wh[idx] = h;
        Wl[idx] = f2bf_rne(acc[oo] - bf2f(h));
    }
}

// ---------------------------------------------------------------------------
// Kernel 1b: X fp32 -> Xh/Xl bf16 trunc-hi/lo split (one pass, memory-bound).
// ---------------------------------------------------------------------------
__global__ __launch_bounds__(256) void xsplit_kernel(
    const float* __restrict__ x0, const float* __restrict__ x1,
    const float* __restrict__ x2,
    u16* __restrict__ Xh, u16* __restrict__ Xl)
{
    int t = blockIdx.y;
    const float* X = (t == 0) ? x0 : ((t == 1) ? x1 : x2);
    u16* oh = Xh + (size_t)t * NROWS * DIM;
    u16* ol = Xl + (size_t)t * NROWS * DIM;
    size_t base = ((size_t)blockIdx.x * 256 + threadIdx.x) * 8;
    float4 a = *(const float4*)(X + base);
    float4 b = *(const float4*)(X + base + 4);
    float v[8] = {a.x, a.y, a.z, a.w, b.x, b.y, b.z, b.w};
    short8 hv, lv;
    #pragma unroll
    for (int e = 0; e < 8; ++e) {
        unsigned u = fbits(v[e]);
        hv[e] = (short)(u >> 16);
        float l = v[e] - asfloat(u & 0xffff0000u);
        lv[e] = (short)(fbits(l) >> 16);
    }
    *(short8*)(oh + base) = hv;
    *(short8*)(ol + base) = lv;
}

// ---------------------------------------------------------------------------
// Kernel 2 (presplit path): pure-staging MFMA GEMM, m97 shape.
// launch_bounds (256,4): VGPR 76 / LDS 32KB both allow 4 blocks/CU; the
// previous (256,3) under-asked. More TLP vs the barrier-drain stall.
// ---------------------------------------------------------------------------
__global__ __launch_bounds__(256, 4) void qkv_mfma_gemm_ps(
    const u16* __restrict__ Xhg, const u16* __restrict__ Xlg,
    const u16* __restrict__ Whg, const u16* __restrict__ Wlg,
    const float* __restrict__ b0, const float* __restrict__ b1,
    const float* __restrict__ b2,
    u16* __restrict__ Qh, u16* __restrict__ Ql,
    u16* __restrict__ Kh, u16* __restrict__ Kl,
    u16* __restrict__ Vb)
{
    unsigned flat = blockIdx.x + 8u * blockIdx.y + 256u * blockIdx.z; // 0..767
    unsigned swz = (flat & 7u) * 96u + (flat >> 3);
    int t = swz >> 8;
    int n0 = (swz & 7u) * 128;
    int m0 = ((swz >> 3) & 31u) * 128;

    const u16* Ah_g = Xhg + (size_t)t * NROWS * DIM;
    const u16* Al_g = Xlg + (size_t)t * NROWS * DIM;
    const u16* Bh_g = Whg + (size_t)t * DIM * DIM;
    const u16* Bl_g = Wlg + (size_t)t * DIM * DIM;
    const float* bias = (t == 0) ? b0 : ((t == 1) ? b1 : b2);

    __shared__ __align__(16) u16 lds[16384];
    u16* sAh = lds;
    u16* sAl = lds + 4096;
    u16* sBh = lds + 8192;
    u16* sBl = lds + 12288;

    int tid = threadIdx.x;
    int w = tid >> 6, lane = tid & 63;
    int c = lane & 15, quad = lane >> 4;
    int mh = (w >> 1) * 64, nh = (w & 1) * 64;

    int srow = lane >> 2, sgr = lane & 3;
    int ssw = sgr ^ ((srow >> 1) & 3);        // pre-swizzled source chunk

    f32x4 acc[4][4];
    #pragma unroll
    for (int i = 0; i < 4; ++i)
        #pragma unroll
        for (int j = 0; j < 4; ++j)
            #pragma unroll
            for (int r = 0; r < 4; ++r) acc[i][j][r] = 0.0f;

    float bias_v[4];
    #pragma unroll
    for (int tn = 0; tn < 4; ++tn) bias_v[tn] = bias[n0 + nh + tn * 16 + c];

    #define STAGE(kg) do {                                                     \
        _Pragma("unroll")                                                      \
        for (int i_ = 0; i_ < 2; ++i_) {                                       \
            int rb = w * 32 + i_ * 16;                                         \
            size_t ro = (size_t)(n0 + rb + srow) * DIM + ((kg) + ssw) * 8;     \
            dma16(Bh_g + ro, sBh + rb * 32);                                   \
            dma16(Bl_g + ro, sBl + rb * 32);                                   \
            size_t ao = (size_t)(m0 + rb + srow) * DIM + ((kg) + ssw) * 8;     \
            dma16(Ah_g + ao, sAh + rb * 32);                                   \
            dma16(Al_g + ao, sAl + rb * 32);                                   \
        }                                                                      \
    } while (0)

    STAGE(0);

    for (int it = 0; it < 32; ++it) {
        __syncthreads();                      // staged tiles landed

        short8 ah[4], al[4], bh[4], bl[4];
        int rsw = (quad ^ ((c >> 1) & 3)) * 8;
        #pragma unroll
        for (int tt = 0; tt < 4; ++tt) {
            int mi = (mh + tt * 16 + c) * 32 + rsw;
            ah[tt] = *(short8*)(sAh + mi);
            al[tt] = *(short8*)(sAl + mi);
            int ni = (nh + tt * 16 + c) * 32 + rsw;
            bh[tt] = *(short8*)(sBh + ni);
            bl[tt] = *(short8*)(sBl + ni);
        }
        __syncthreads();                      // LDS free for next stage

        if (it < 31) STAGE((it + 1) * 4);

        #pragma unroll
        for (int tm = 0; tm < 4; ++tm)
            #pragma unroll
            for (int tn = 0; tn < 4; ++tn) {
                acc[tm][tn] = __builtin_amdgcn_mfma_f32_16x16x32_bf16(
                    ah[tm], bh[tn], acc[tm][tn], 0, 0, 0);
                acc[tm][tn] = __builtin_amdgcn_mfma_f32_16x16x32_bf16(
                    ah[tm], bl[tn], acc[tm][tn], 0, 0, 0);
                acc[tm][tn] = __builtin_amdgcn_mfma_f32_16x16x32_bf16(
                    al[tm], bh[tn], acc[tm][tn], 0, 0, 0);
            }
    }
    #undef STAGE

    // ---- epilogue: trunc-hi/lo split; Q pre-scaled by CSCALE ----
    if (t < 2) {
        u16* Yh = (t == 0) ? Qh : Kh;
        u16* Yl = (t == 0) ? Ql : Kl;
        float qs = (t == 0) ? CSCALE : 1.0f;
        #pragma unroll
        for (int tm = 0; tm < 4; ++tm)
            #pragma unroll
            for (int r = 0; r < 4; ++r) {
                int m = m0 + mh + tm * 16 + quad * 4 + r;
                #pragma unroll
                for (int tn = 0; tn < 4; ++tn) {
                    int n = n0 + nh + tn * 16 + c;
                    float o = (acc[tm][tn][r] + bias_v[tn]) * qs;
                    unsigned bo = fbits(o);
                    Yh[(size_t)m * DIM + n] = (u16)(bo >> 16);
                    float l = o - asfloat(bo & 0xffff0000u);
                    Yl[(size_t)m * DIM + n] = (u16)(fbits(l) >> 16);
                }
            }
    } else {
        #pragma unroll
        for (int tm = 0; tm < 4; ++tm)
            #pragma unroll
            for (int r = 0; r < 4; ++r) {
                int m = m0 + mh + tm * 16 + quad * 4 + r;
                #pragma unroll
                for (int tn = 0; tn < 4; ++tn) {
                    int n = n0 + nh + tn * 16 + c;
                    Vb[(size_t)m * DIM + n] =
                        (u16)(fbits(acc[tm][tn][r] + bias_v[tn]) >> 16);
                }
            }
    }
}

// ---------------------------------------------------------------------------
// Kernel 2 (fallback): in-loop A split. Used only when ws can't hold Xh/Xl.
// ---------------------------------------------------------------------------
__global__ __launch_bounds__(256, 3) void qkv_mfma_gemm_fb(
    const float* __restrict__ x0, const float* __restrict__ x1,
    const float* __restrict__ x2,
    const u16* __restrict__ Whg, const u16* __restrict__ Wlg,
    const float* __restrict__ b0, const float* __restrict__ b1,
    const float* __restrict__ b2,
    u16* __restrict__ Qh, u16* __restrict__ Ql,
    u16* __restrict__ Kh, u16* __restrict__ Kl,
    u16* __restrict__ Vb)
{
    unsigned flat = blockIdx.x + 8u * blockIdx.y + 256u * blockIdx.z;
    unsigned swz = (flat & 7u) * 96u + (flat >> 3);
    int t = swz >> 8;
    int n0 = (swz & 7u) * 128;
    int m0 = ((swz >> 3) & 31u) * 128;

    const float* X    = (t == 0) ? x0 : ((t == 1) ? x1 : x2);
    const u16* Bh_g   = Whg + (size_t)t * DIM * DIM;
    const u16* Bl_g   = Wlg + (size_t)t * DIM * DIM;
    const float* bias = (t == 0) ? b0 : ((t == 1) ? b1 : b2);

    __shared__ __align__(16) u16 lds[16384];
    u16* sAh = lds;
    u16* sAl = lds + 4096;
    u16* sBh = lds + 8192;
    u16* sBl = lds + 12288;

    int tid = threadIdx.x;
    int w = tid >> 6, lane = tid & 63;
    int c = lane & 15, quad = lane >> 4;
    int mh = (w >> 1) * 64, nh = (w & 1) * 64;

    int arow = w * 32 + (lane & 31);
    int acol = (lane >> 5) * 16;
    const float* aptr = X + (size_t)(m0 + arow) * DIM + acol;
    int awz = (arow >> 1) & 3;

    int srow = lane >> 2, sgr = lane & 3;
    int bsw = sgr ^ ((srow >> 1) & 3);

    f32x4 acc[4][4];
    #pragma unroll
    for (int i = 0; i < 4; ++i)
        #pragma unroll
        for (int j = 0; j < 4; ++j)
            #pragma unroll
            for (int r = 0; r < 4; ++r) acc[i][j][r] = 0.0f;

    float bias_v[4];
    #pragma unroll
    for (int tn = 0; tn < 4; ++tn) bias_v[tn] = bias[n0 + nh + tn * 16 + c];

    float4 xa[4];
    #pragma unroll
    for (int i = 0; i < 2; ++i) {
        int rb = w * 32 + i * 16;
        const u16* gh = Bh_g + (size_t)(n0 + rb + srow) * DIM + bsw * 8;
        const u16* gl = Bl_g + (size_t)(n0 + rb + srow) * DIM + bsw * 8;
        dma16(gh, sBh + rb * 32);
        dma16(gl, sBl + rb * 32);
    }
    #pragma unroll
    for (int j = 0; j < 4; ++j) xa[j] = *(const float4*)(aptr + j * 4);

    for (int it = 0; it < 32; ++it) {
        #pragma unroll
        for (int g = 0; g < 2; ++g) {
            float v[8] = { xa[2*g].x, xa[2*g].y, xa[2*g].z, xa[2*g].w,
                           xa[2*g+1].x, xa[2*g+1].y, xa[2*g+1].z, xa[2*g+1].w };
            short8 hv, lv;
            #pragma unroll
            for (int e = 0; e < 8; ++e) {
                unsigned u = fbits(v[e]);
                hv[e] = (short)(u >> 16);
                float l = v[e] - asfloat(u & 0xffff0000u);
                lv[e] = (short)(fbits(l) >> 16);
            }
            int chunk = (((lane >> 5) * 2 + g) ^ awz) * 8;
            *(short8*)(sAh + arow * 32 + chunk) = hv;
            *(short8*)(sAl + arow * 32 + chunk) = lv;
        }
        __syncthreads();

        short8 ah[4], al[4], bh[4], bl[4];
        int rsw = (quad ^ ((c >> 1) & 3)) * 8;
        #pragma unroll
        for (int tt = 0; tt < 4; ++tt) {
            int mi = (mh + tt * 16 + c) * 32 + rsw;
            ah[tt] = *(short8*)(sAh + mi);
            al[tt] = *(short8*)(sAl + mi);
            int ni = (nh + tt * 16 + c) * 32 + rsw;
            bh[tt] = *(short8*)(sBh + ni);
            bl[tt] = *(short8*)(sBl + ni);
        }
        __syncthreads();

        if (it < 31) {
            int kg = (it + 1) * 4;
            #pragma unroll
            for (int i = 0; i < 2; ++i) {
                int rb = w * 32 + i * 16;
                const u16* gh = Bh_g + (size_t)(n0 + rb + srow) * DIM + (kg + bsw) * 8;
                const u16* gl = Bl_g + (size_t)(n0 + rb + srow) * DIM + (kg + bsw) * 8;
                dma16(gh, sBh + rb * 32);
                dma16(gl, sBl + rb * 32);
            }
            #pragma unroll
            for (int j = 0; j < 4; ++j)
                xa[j] = *(const float4*)(aptr + (it + 1) * 32 + j * 4);
        }

        #pragma unroll
        for (int tm = 0; tm < 4; ++tm)
            #pragma unroll
            for (int tn = 0; tn < 4; ++tn) {
                acc[tm][tn] = __builtin_amdgcn_mfma_f32_16x16x32_bf16(
                    ah[tm], bh[tn], acc[tm][tn], 0, 0, 0);
                acc[tm][tn] = __builtin_amdgcn_mfma_f32_16x16x32_bf16(
                    ah[tm], bl[tn], acc[tm][tn], 0, 0, 0);
                acc[tm][tn] = __builtin_amdgcn_mfma_f32_16x16x32_bf16(
                    al[tm], bh[tn], acc[tm][tn], 0, 0, 0);
            }
    }

    if (t < 2) {
        u16* Yh = (t == 0) ? Qh : Kh;
        u16* Yl = (t == 0) ? Ql : Kl;
        float qs = (t == 0) ? CSCALE : 1.0f;
        #pragma unroll
        for (int tm = 0; tm < 4; ++tm)
            #pragma unroll
            for (int r = 0; r < 4; ++r) {
                int m = m0 + mh + tm * 16 + quad * 4 + r;
                #pragma unroll
                for (int tn = 0; tn < 4; ++tn) {
                    int n = n0 + nh + tn * 16 + c;
                    float o = (acc[tm][tn][r] + bias_v[tn]) * qs;
                    unsigned bo = fbits(o);
                    Yh[(size_t)m * DIM + n] = (u16)(bo >> 16);
                    float l = o - asfloat(bo & 0xffff0000u);
                    Yl[(size_t)m * DIM + n] = (u16)(fbits(l) >> 16);
                }
            }
    } else {
        #pragma unroll
        for (int tm = 0; tm < 4; ++tm)
            #pragma unroll
            for (int r = 0; r < 4; ++r) {
                int m = m0 + mh + tm * 16 + quad * 4 + r;
                #pragma unroll
                for (int tn = 0; tn < 4; ++tn) {
                    int n = n0 + nh + tn * 16 + c;
                    Vb[(size_t)m * DIM + n] =
                        (u16)(fbits(acc[tm][tn][r] + bias_v[tn]) >> 16);
                }
            }
    }
}

// ---------------------------------------------------------------------------
// Kernel 3: V bf16 [s*B+b][h*64+d] -> Vt bf16 [b][h][d][s]
// ---------------------------------------------------------------------------
__global__ __launch_bounds__(256) void vt_kernel(
    const u16* __restrict__ Vb, u16* __restrict__ Vt)
{
    int b = blockIdx.z, h = blockIdx.y, s0 = blockIdx.x * 64;
    __shared__ __align__(16) u16 tile[64][80];
    int tid = threadIdx.x;
    int sl = tid >> 2, d0 = (tid & 3) * 16;
    const u16* src = Vb + (size_t)((s0 + sl) * BATCH + b) * DIM + h * HD + d0;
    short8 v0 = *(const short8*)src;
    short8 v1 = *(const short8*)(src + 8);
    #pragma unroll
    for (int j = 0; j < 8; ++j) {
        tile[d0 + j][sl] = (u16)v0[j];
        tile[d0 + 8 + j][sl] = (u16)v1[j];
    }
    __syncthreads();
    int d = tid >> 2, sc0 = (tid & 3) * 16;
    u16* dst = Vt + (size_t)((b * NHEAD + h) * HD + d) * SLEN + s0 + sc0;
    *(short8*)dst = *(const short8*)&tile[d][sc0];
    *(short8*)(dst + 8) = *(const short8*)&tile[d][sc0 + 8];
}

// ---------------------------------------------------------------------------
// Kernel 4: MFMA flash attention v10 (unchanged from R9 — attn counters were
// clean; only the prep fusion regressed): transposed PV, raw v_exp_f32,
// v_perm packing, deferred l-reduction, wave-private sP, defer-rescale,
// setprio, XCD swizzle. 512 threads, 16 waves/CU.
// ---------------------------------------------------------------------------
__global__ __launch_bounds__(512, 4) void attn_mfma_kernel(
    const u16* __restrict__ Qh, const u16* __restrict__ Ql,
    const u16* __restrict__ Kh, const u16* __restrict__ Kl,
    const u16* __restrict__ Vt, float* __restrict__ out)
{
    unsigned flat = blockIdx.x + 16u * blockIdx.y + 256u * blockIdx.z; // 0..511
    unsigned swz = (flat & 7u) * 64u + (flat >> 3);
    int q0 = (swz & 15u) * 128;
    int h = (swz >> 4) & 15u;
    int b = swz >> 8;

    int tid = threadIdx.x;
    int w = tid >> 6, lane = tid & 63;
    int c = lane & 15, quad = lane >> 4;

    __shared__ __align__(16) u16 sbuf[2][3][4096];
    __shared__ __align__(16) u16 sP[8][1024];

    short8 qhf[2], qlf[2];
    {
        int s = q0 + w * 16 + c;
        size_t base = (size_t)(s * BATCH + b) * DIM + h * HD + quad * 8;
        qhf[0] = *(const short8*)(Qh + base);
        qhf[1] = *(const short8*)(Qh + base + 32);
        qlf[0] = *(const short8*)(Ql + base);
        qlf[1] = *(const short8*)(Ql + base + 32);
    }

    f32x4 acc[4];
    #pragma unroll
    for (int i = 0; i < 4; ++i)
        #pragma unroll
        for (int r = 0; r < 4; ++r) acc[i][r] = 0.0f;
    float m_run = -1e38f, lsum = 0.0f;   // lsum: per-lane partial (own 16 keys)

    int r3 = lane >> 3, c3 = lane & 7;
    int sw = c3 ^ r3;
    const size_t bhofs = (size_t)(b * NHEAD + h) * HD;

    #define ISSUE_DMA(n0v, bufv) do {                                          \
        int row_ = w * 8 + r3;                                                 \
        size_t gk = (size_t)(((n0v) + row_) * BATCH + b) * DIM + h * HD + sw * 8; \
        dma16(Kh + gk, &sbuf[bufv][0][w * 512]);                               \
        dma16(Kl + gk, &sbuf[bufv][1][w * 512]);                               \
        size_t gv = (bhofs + row_) * SLEN + (n0v) + sw * 8;                    \
        dma16(Vt + gv, &sbuf[bufv][2][w * 512]);                               \
    } while (0)

    ISSUE_DMA(0, 0);

    for (int it = 0; it < 32; ++it) {
        int cur = it & 1;
        __syncthreads();
        if (it < 31) ISSUE_DMA((it + 1) * 64, cur ^ 1);

        const u16* bKh = sbuf[cur][0];
        const u16* bKl = sbuf[cur][1];
        const u16* bVt = sbuf[cur][2];

        // ---- T = K·Q^T : lane gets T[key=ct*16+quad*4+r][q=c] ----
        f32x4 sc[4];
        #pragma unroll
        for (int ct = 0; ct < 4; ++ct) {
            int row = ct * 16 + c, rw = row & 7;
            int kb = row * 64;
            short8 kh0 = *(const short8*)(bKh + kb + ((quad ^ rw) * 8));
            short8 kh1 = *(const short8*)(bKh + kb + (((4 + quad) ^ rw) * 8));
            short8 kl0 = *(const short8*)(bKl + kb + ((quad ^ rw) * 8));
            short8 kl1 = *(const short8*)(bKl + kb + (((4 + quad) ^ rw) * 8));
            __builtin_amdgcn_s_setprio(1);
            f32x4 s = {0.0f, 0.0f, 0.0f, 0.0f};
            s = __builtin_amdgcn_mfma_f32_16x16x32_bf16(kh0, qhf[0], s, 0, 0, 0);
            s = __builtin_amdgcn_mfma_f32_16x16x32_bf16(kh1, qhf[1], s, 0, 0, 0);
            s = __builtin_amdgcn_mfma_f32_16x16x32_bf16(kh0, qlf[0], s, 0, 0, 0);
            s = __builtin_amdgcn_mfma_f32_16x16x32_bf16(kh1, qlf[1], s, 0, 0, 0);
            s = __builtin_amdgcn_mfma_f32_16x16x32_bf16(kl0, qhf[0], s, 0, 0, 0);
            s = __builtin_amdgcn_mfma_f32_16x16x32_bf16(kl1, qhf[1], s, 0, 0, 0);
            __builtin_amdgcn_s_setprio(0);
            sc[ct] = s;
        }

        // ---- V fragments hoisted: ds_read latency hides under softmax ----
        short8 vv[4][2];
        #pragma unroll
        for (int ctd = 0; ctd < 4; ++ctd) {
            int vrow = ctd * 16 + c, vrw = vrow & 7;
            int vb = vrow * 64;
            vv[ctd][0] = *(const short8*)(bVt + vb + ((quad ^ vrw) * 8));
            vv[ctd][1] = *(const short8*)(bVt + vb + (((4 + quad) ^ vrw) * 8));
        }

        // ---- online softmax + P pack -> wave-private swizzled LDS ----
        u16* wp = sP[w];
        short8 pf0, pf1;
        {
            float m00 = fmaxf(fmaxf(sc[0][0], sc[0][1]), fmaxf(sc[0][2], sc[0][3]));
            float m01 = fmaxf(fmaxf(sc[1][0], sc[1][1]), fmaxf(sc[1][2], sc[1][3]));
            float m10 = fmaxf(fmaxf(sc[2][0], sc[2][1]), fmaxf(sc[2][2], sc[2][3]));
            float m11 = fmaxf(fmaxf(sc[3][0], sc[3][1]), fmaxf(sc[3][2], sc[3][3]));
            float pm = fmaxf(fmaxf(m00, m01), fmaxf(m10, m11));
            pm = fmaxf(pm, __shfl_xor(pm, 16));
            pm = fmaxf(pm, __shfl_xor(pm, 32));
            float mnew = fmaxf(m_run, pm);
            bool noresc = __all(pm <= m_run);
            if (!noresc) {
                float al = __builtin_amdgcn_exp2f(m_run - mnew);
                #pragma unroll
                for (int ctd = 0; ctd < 4; ++ctd)
                    #pragma unroll
                    for (int r = 0; r < 4; ++r) acc[ctd][r] *= al;
                lsum *= al;
            }
            m_run = mnew;

            float psp[4];
            int prow = c * 64;
            #pragma unroll
            for (int ct = 0; ct < 4; ++ct) {
                float p0 = __builtin_amdgcn_exp2f(sc[ct][0] - mnew);
                float p1 = __builtin_amdgcn_exp2f(sc[ct][1] - mnew);
                float p2 = __builtin_amdgcn_exp2f(sc[ct][2] - mnew);
                float p3 = __builtin_amdgcn_exp2f(sc[ct][3] - mnew);
                psp[ct] = (p0 + p1) + (p2 + p3);
                uint2v pk;
                pk.x = __builtin_amdgcn_perm(fbits(p1), fbits(p0), 0x07060302u);
                pk.y = __builtin_amdgcn_perm(fbits(p3), fbits(p2), 0x07060302u);
                int phys = (ct * 2 + (quad >> 1)) ^ (c & 7);
                *(uint2v*)(wp + prow + phys * 8 + (quad & 1) * 4) = pk;
            }
            lsum += (psp[0] + psp[1]) + (psp[2] + psp[3]);

            int rw = c & 7;
            pf0 = *(const short8*)(wp + prow + ((quad ^ rw) * 8));
            pf1 = *(const short8*)(wp + prow + (((4 + quad) ^ rw) * 8));
        }

        // ---- O^T += V^T·P^T : A=vv (V^T rows d), B=pf (P^T cols q=c) ----
        __builtin_amdgcn_s_setprio(1);
        #pragma unroll
        for (int ctd = 0; ctd < 4; ++ctd) {
            acc[ctd] = __builtin_amdgcn_mfma_f32_16x16x32_bf16(
                vv[ctd][0], pf0, acc[ctd], 0, 0, 0);
            acc[ctd] = __builtin_amdgcn_mfma_f32_16x16x32_bf16(
                vv[ctd][1], pf1, acc[ctd], 0, 0, 0);
        }
        __builtin_amdgcn_s_setprio(0);
    }
    #undef ISSUE_DMA

    // ---- epilogue: reduce l across the 4 quads (q=c), float4 stores ----
    {
        float lt = lsum;
        lt += __shfl_xor(lt, 16);
        lt += __shfl_xor(lt, 32);
        float rli = 1.0f / lt;
        int s = q0 + w * 16 + c;
        float* obase = out + (size_t)(s * BATCH + b) * DIM + h * HD + quad * 4;
        #pragma unroll
        for (int ctd = 0; ctd < 4; ++ctd) {
            float4 ov;
            ov.x = acc[ctd][0] * rli;
            ov.y = acc[ctd][1] * rli;
            ov.z = acc[ctd][2] * rli;
            ov.w = acc[ctd][3] * rli;
            *(float4*)(obase + ctd * 16) = ov;
        }
    }
}

// ---------------------------------------------------------------------------
extern "C" void kernel_launch(void* const* d_in, const int* in_sizes, int n_in,
                              void* d_out, int out_size, void* d_ws, size_t ws_size,
                              hipStream_t stream)
{
    const float* query = (const float*)d_in[0];
    const float* key_  = (const float*)d_in[1];
    const float* value = (const float*)d_in[2];
    const float* tmpl  = (const float*)d_in[3];
    const float* wq_cw = (const float*)d_in[4];
    const float* wq_cb = (const float*)d_in[5];
    const float* wq_b  = (const float*)d_in[6];
    const float* wk_cw = (const float*)d_in[7];
    const float* wk_cb = (const float*)d_in[8];
    const float* wk_b  = (const float*)d_in[9];
    const float* wv_cw = (const float*)d_in[10];
    const float* wv_cb = (const float*)d_in[11];
    const float* wv_b  = (const float*)d_in[12];

    char* ws = (char*)d_ws;
    u16* Wh = (u16*)(ws);
    u16* Wl = (u16*)(ws + 6291456);
    u16* Qh = (u16*)(ws + 12582912);
    u16* Ql = (u16*)(ws + 20971520);
    u16* Kh = (u16*)(ws + 29360128);
    u16* Kl = (u16*)(ws + 37748736);
    u16* Vb = (u16*)(ws + 46137344);
    u16* Vt = (u16*)(ws + 54525952);
    u16* Xh = (u16*)(ws + 62914560);           // 3*4096*1024*2 = 25165824
    u16* Xl = (u16*)(ws + 88080384);           // ends at 113246208
    float* out = (float*)d_out;

    bool presplit = ws_size >= 113246208ull;

    conv_weight_kernel<<<dim3(DIM / 256, DIM / 4, 3), 256, 0, stream>>>(
        tmpl, wq_cw, wq_cb, wk_cw, wk_cb, wv_cw, wv_cb, Wh, Wl);

    if (presplit) {
        xsplit_kernel<<<dim3(NROWS * DIM / (256 * 8), 3), 256, 0, stream>>>(
            query, key_, value, Xh, Xl);
        qkv_mfma_gemm_ps<<<dim3(DIM / 128, NROWS / 128, 3), 256, 0, stream>>>(
            Xh, Xl, Wh, Wl, wq_b, wk_b, wv_b, Qh, Ql, Kh, Kl, Vb);
    } else {
        qkv_mfma_gemm_fb<<<dim3(DIM / 128, NROWS / 128, 3), 256, 0, stream>>>(
            query, key_, value, Wh, Wl, wq_b, wk_b, wv_b, Qh, Ql, Kh, Kl, Vb);
    }

    vt_kernel<<<dim3(SLEN / 64, NHEAD, BATCH), 256, 0, stream>>>(Vb, Vt);

    attn_mfma_kernel<<<dim3(SLEN / 128, NHEAD, BATCH), 512, 0, stream>>>(
        Qh, Ql, Kh, Kl, Vt, out);
}